// Round 1
// baseline (454.121 us; speedup 1.0000x reference)
//
#include <hip/hip_runtime.h>
#include <hip/hip_bf16.h>

// ENN_20203526160942 — fp32 baseline.
// Stage 1 (prep):  H = LM[cat];  preI = H@W1i;  prejb = H@W1j + be1
// Stage 2 (pairs): V[i] = sum_{j != i} sum_l tanh( (tanh(preI_i + prejb_j + d2_ij*w1z)) @ We2 + be2 )[l]
// Stage 3 (post):  newH = tanh( tanh(H@Wh1[:64] + V*Wh1[64] + bh1) @ Wh2 + bh2 )
// Stage 4 (finish): out = (sum_i newH[i]) @ Wo + bo

#define N_ATOMS 1024
#define L_DIM 64

__device__ __forceinline__ float tanh_fast(float x) {
    // tanh(x) = 1 - 2/(exp(2x)+1); exp(2x) = exp2(x * 2*log2(e))
    float e = __builtin_amdgcn_exp2f(x * 2.8853900817779268f);
    float r = __builtin_amdgcn_rcpf(e + 1.0f);
    return fmaf(-2.0f, r, 1.0f);   // large x: e=inf -> r=0 -> 1; very neg: e=0 -> r=1 -> -1
}

// ---------------- Stage 1: prep ----------------
__global__ __launch_bounds__(64) void k_prep(const int* __restrict__ cat,
                                             const float* __restrict__ LM,
                                             const float* __restrict__ We1,
                                             const float* __restrict__ be1,
                                             float* __restrict__ H,
                                             float* __restrict__ preI,
                                             float* __restrict__ prejb) {
    int i = blockIdx.x;
    int l = threadIdx.x;
    __shared__ float hrow[L_DIM];
    int c = cat[i];
    float hv = LM[c * L_DIM + l];
    hrow[l] = hv;
    H[i * L_DIM + l] = hv;
    __syncthreads();
    float s1 = 0.f, s2 = 0.f;
#pragma unroll
    for (int m = 0; m < L_DIM; m++) {
        float h = hrow[m];
        s1 = fmaf(h, We1[m * L_DIM + l], s1);
        s2 = fmaf(h, We1[(L_DIM + m) * L_DIM + l], s2);
    }
    preI[i * L_DIM + l] = s1;
    prejb[i * L_DIM + l] = s2 + be1[l];
}

// ---------------- Stage 2: pairs (the hot kernel) ----------------
#define PAIRS_TPB 256
__global__ __launch_bounds__(PAIRS_TPB) void k_pairs(const float* __restrict__ Z,
                                                     const float* __restrict__ We1,
                                                     const float* __restrict__ We2,
                                                     const float* __restrict__ be2,
                                                     const float* __restrict__ preI,
                                                     const float* __restrict__ prejb,
                                                     float* __restrict__ V) {
    int i = blockIdx.x;
    int t = threadIdx.x;

    __shared__ float we2T[L_DIM * L_DIM];   // we2T[l][m] = We2[m][l]
    __shared__ float aI[L_DIM];             // preI row i
    __shared__ float w1z[L_DIM];
    __shared__ float be2s[L_DIM];
    __shared__ float red[PAIRS_TPB];

    for (int p = t; p < L_DIM * L_DIM; p += PAIRS_TPB) {
        int l = p >> 6, m = p & 63;
        we2T[l * L_DIM + m] = We2[m * L_DIM + l];
    }
    if (t < L_DIM) {
        aI[t]   = preI[i * L_DIM + t];
        w1z[t]  = We1[2 * L_DIM * L_DIM + t];   // row 128 of We1
        be2s[t] = be2[t];
    }
    float zi0 = Z[i * 3 + 0], zi1 = Z[i * 3 + 1], zi2 = Z[i * 3 + 2];
    __syncthreads();

    float Vacc = 0.f;
    for (int j = t; j < N_ATOMS; j += PAIRS_TPB) {
        float d0 = zi0 - Z[j * 3 + 0];
        float d1 = zi1 - Z[j * 3 + 1];
        float d2c = zi2 - Z[j * 3 + 2];
        float d2 = d0 * d0 + d1 * d1 + d2c * d2c;

        // h1 for this (i,j): 64 values in registers
        float h1v[L_DIM];
        const float4* pj4 = (const float4*)(prejb + j * L_DIM);
        const float4* aI4 = (const float4*)aI;
        const float4* wz4 = (const float4*)w1z;
#pragma unroll
        for (int m4 = 0; m4 < 16; m4++) {
            float4 pj = pj4[m4];
            float4 av = aI4[m4];
            float4 wz = wz4[m4];
            h1v[4 * m4 + 0] = tanh_fast(fmaf(d2, wz.x, av.x + pj.x));
            h1v[4 * m4 + 1] = tanh_fast(fmaf(d2, wz.y, av.y + pj.y));
            h1v[4 * m4 + 2] = tanh_fast(fmaf(d2, wz.z, av.z + pj.z));
            h1v[4 * m4 + 3] = tanh_fast(fmaf(d2, wz.w, av.w + pj.w));
        }

        // s = sum_l tanh( h1 . we2T[l] + be2[l] )
        float s = 0.f;
#pragma unroll 2
        for (int l = 0; l < L_DIM; l++) {
            const float4* wrow = (const float4*)(we2T + l * L_DIM);
            float a0 = 0.f, a1 = 0.f, a2 = 0.f, a3 = 0.f;
#pragma unroll
            for (int m4 = 0; m4 < 16; m4++) {
                float4 w = wrow[m4];
                a0 = fmaf(h1v[4 * m4 + 0], w.x, a0);
                a1 = fmaf(h1v[4 * m4 + 1], w.y, a1);
                a2 = fmaf(h1v[4 * m4 + 2], w.z, a2);
                a3 = fmaf(h1v[4 * m4 + 3], w.w, a3);
            }
            s += tanh_fast(((a0 + a1) + (a2 + a3)) + be2s[l]);
        }
        if (j != i) Vacc += s;
    }

    red[t] = Vacc;
    __syncthreads();
    if (t < 64) {
        float r = red[t] + red[t + 64] + red[t + 128] + red[t + 192];
#pragma unroll
        for (int o = 32; o > 0; o >>= 1) r += __shfl_down(r, o);
        if (t == 0) V[i] = r;
    }
}

// ---------------- Stage 3: post ----------------
__global__ __launch_bounds__(64) void k_post(const float* __restrict__ H,
                                             const float* __restrict__ V,
                                             const float* __restrict__ Wh1,
                                             const float* __restrict__ bh1,
                                             const float* __restrict__ Wh2,
                                             const float* __restrict__ bh2,
                                             float* __restrict__ newH) {
    int i = blockIdx.x;
    int l = threadIdx.x;
    __shared__ float hrow[L_DIM];
    __shared__ float hh[L_DIM];
    hrow[l] = H[i * L_DIM + l];
    __syncthreads();
    float s = 0.f;
#pragma unroll
    for (int m = 0; m < L_DIM; m++) s = fmaf(hrow[m], Wh1[m * L_DIM + l], s);
    float v = V[i];
    s = fmaf(v, Wh1[L_DIM * L_DIM + l], s) + bh1[l];
    hh[l] = tanh_fast(s);
    __syncthreads();
    float s2 = 0.f;
#pragma unroll
    for (int m = 0; m < L_DIM; m++) s2 = fmaf(hh[m], Wh2[m * L_DIM + l], s2);
    newH[i * L_DIM + l] = tanh_fast(s2 + bh2[l]);
}

// ---------------- Stage 4: finish ----------------
__global__ __launch_bounds__(256) void k_finish(const float* __restrict__ newH,
                                                const float* __restrict__ Wo,
                                                const float* __restrict__ bo,
                                                float* __restrict__ out) {
    int t = threadIdx.x;
    int l = t & 63;
    int q = t >> 6;
    float s = 0.f;
    for (int j = q * (N_ATOMS / 4); j < (q + 1) * (N_ATOMS / 4); j++)
        s += newH[j * L_DIM + l];
    __shared__ float red[256];
    red[t] = s;
    __syncthreads();
    if (t < 64) {
        float hs = red[t] + red[t + 64] + red[t + 128] + red[t + 192];
        float w = hs * Wo[l];
#pragma unroll
        for (int o = 32; o > 0; o >>= 1) w += __shfl_down(w, o);
        if (t == 0) out[0] = w + bo[0];
    }
}

extern "C" void kernel_launch(void* const* d_in, const int* in_sizes, int n_in,
                              void* d_out, int out_size, void* d_ws, size_t ws_size,
                              hipStream_t stream) {
    const int*   cat = (const int*)  d_in[0];
    const float* Z   = (const float*)d_in[1];
    const float* LM  = (const float*)d_in[2];
    const float* We1 = (const float*)d_in[3];
    const float* be1 = (const float*)d_in[4];
    const float* We2 = (const float*)d_in[5];
    const float* be2 = (const float*)d_in[6];
    const float* Wh1 = (const float*)d_in[7];
    const float* bh1 = (const float*)d_in[8];
    const float* Wh2 = (const float*)d_in[9];
    const float* bh2 = (const float*)d_in[10];
    const float* Wo  = (const float*)d_in[11];
    const float* bo  = (const float*)d_in[12];
    float* out = (float*)d_out;

    // workspace layout (floats)
    float* ws    = (float*)d_ws;
    float* H     = ws;                       // 1024*64
    float* preI  = H     + N_ATOMS * L_DIM;  // 1024*64
    float* prejb = preI  + N_ATOMS * L_DIM;  // 1024*64
    float* V     = prejb + N_ATOMS * L_DIM;  // 1024
    float* newH  = V     + N_ATOMS;          // 1024*64

    k_prep<<<N_ATOMS, 64, 0, stream>>>(cat, LM, We1, be1, H, preI, prejb);
    k_pairs<<<N_ATOMS, PAIRS_TPB, 0, stream>>>(Z, We1, We2, be2, preI, prejb, V);
    k_post<<<N_ATOMS, 64, 0, stream>>>(H, V, Wh1, bh1, Wh2, bh2, newH);
    k_finish<<<1, 256, 0, stream>>>(newH, Wo, bo, out);
}

// Round 2
// 143.061 us; speedup vs baseline: 3.1743x; 3.1743x over previous
//
#include <hip/hip_runtime.h>
#include <hip/hip_bf16.h>

// ENN_20203526160942 — MFMA (split-f16 x3) version.
// Stage 1 (prep):   H = LM[cat]; preI = H@W1i; P3 = pack(H@W1j + be1) in MFMA A-frag order
// Stage 2 (pairs):  per i: S[j,:] = tanh(h1) @ We2 via 16x16x32 f16 MFMA (hi/lo split x3),
//                   V[i] = sum_{j!=i} sum_l tanh(S[j,l] + be2[l])
// Stage 3 (postfin): newH = tanh(tanh(H@Wh1[:64] + V*Wh1[64] + bh1)@Wh2 + bh2);
//                    out = sum_i newH[i]@Wo + bo  (block-reduce + atomicAdd)

#define N_ATOMS 1024
#define L_DIM 64
#define TPB 256

typedef _Float16 f16x8 __attribute__((ext_vector_type(8)));
typedef float f32x4 __attribute__((ext_vector_type(4)));

__device__ __forceinline__ float tanh_fast(float x) {
    // tanh(x) = 1 - 2/(exp(2x)+1); exp(2x) = exp2(x * 2*log2(e))
    float e = __builtin_amdgcn_exp2f(x * 2.8853900817779268f);
    float r = __builtin_amdgcn_rcpf(e + 1.0f);
    return fmaf(-2.0f, r, 1.0f);   // e=inf -> 1; e=0 -> -1
}

// ---------------- Stage 1: prep ----------------
// 256 blocks x 256 threads, 4 atoms per block.
__global__ __launch_bounds__(256) void k_prep(const int* __restrict__ cat,
                                              const float* __restrict__ LM,
                                              const float* __restrict__ We1,
                                              const float* __restrict__ be1,
                                              float* __restrict__ H,
                                              float* __restrict__ preI,
                                              float* __restrict__ P3) {
    int t = threadIdx.x;
    int sub = t >> 6, l = t & 63;
    int i = blockIdx.x * 4 + sub;
    __shared__ float hrow[4][L_DIM];
    float hv = LM[cat[i] * L_DIM + l];
    hrow[sub][l] = hv;
    H[i * L_DIM + l] = hv;
    __syncthreads();
    float s1 = 0.f, s2 = 0.f;
#pragma unroll
    for (int m = 0; m < L_DIM; m++) {
        float h = hrow[sub][m];
        s1 = fmaf(h, We1[m * L_DIM + l], s1);
        s2 = fmaf(h, We1[(L_DIM + m) * L_DIM + l], s2);
    }
    preI[i * L_DIM + l] = s1;
    // pack prejb[i][l] into A-fragment order:
    // chunk cc=i>>4; lane L=quad*16+(i&15) with quad=(m>>3)&3; group g=(m>>5)*2+((m>>2)&1); e2=m&3
    int cc = i >> 4;
    int Ll = i & 15;
    int quad = (l >> 3) & 3;
    int L = quad * 16 + Ll;
    int g = ((l >> 5) << 1) | ((l >> 2) & 1);
    int e2 = l & 3;
    P3[cc * 1024 + g * 256 + L * 4 + e2] = s2 + be1[l];
}

// ---------------- Stage 2: pairs (MFMA) ----------------
__global__ __launch_bounds__(TPB) void k_pairs(const float* __restrict__ Z,
                                               const float* __restrict__ We1,
                                               const float* __restrict__ We2,
                                               const float* __restrict__ be2,
                                               const float* __restrict__ preI,
                                               const float* __restrict__ P3,
                                               float* __restrict__ V) {
    int i = blockIdx.x;
    int t = threadIdx.x;
    int lane = t & 63;
    int wave = t >> 6;
    int nlo = lane & 15;    // A-row (j-local) / B-col (l-local) / C-col
    int quad = lane >> 4;

    __shared__ float d2s[N_ATOMS];
    __shared__ float red[TPB];

    // d2 table for this i
    float zi0 = Z[i * 3], zi1 = Z[i * 3 + 1], zi2 = Z[i * 3 + 2];
    for (int p = t; p < N_ATOMS; p += TPB) {
        float a = zi0 - Z[p * 3], b = zi1 - Z[p * 3 + 1], c = zi2 - Z[p * 3 + 2];
        d2s[p] = a * a + b * b + c * c;
    }

    // per-lane constants: aI[m], w1z[m] at m = (g>>1)*32 + quad*8 + (g&1)*4 + e2
    f32x4 aiR[4], wzR[4];
#pragma unroll
    for (int g = 0; g < 4; g++) {
        int mb = ((g >> 1) << 5) + (quad << 3) + ((g & 1) << 2);
        aiR[g] = *(const f32x4*)(preI + i * L_DIM + mb);
        wzR[g] = *(const f32x4*)(We1 + 2 * L_DIM * L_DIM + mb);
    }
    float be2R[4];
#pragma unroll
    for (int nt = 0; nt < 4; nt++) be2R[nt] = be2[nt * 16 + nlo];

    // B fragments (We2, hi/lo split), register resident: B[k][n], k = kt*32+quad*8+e, n = nt*16+nlo
    f16x8 bH[4][2], bL[4][2];
#pragma unroll
    for (int nt = 0; nt < 4; nt++)
#pragma unroll
        for (int kt = 0; kt < 2; kt++)
#pragma unroll
            for (int e = 0; e < 8; e++) {
                float w = We2[(kt * 32 + quad * 8 + e) * L_DIM + nt * 16 + nlo];
                _Float16 hi = (_Float16)w;
                bH[nt][kt][e] = hi;
                bL[nt][kt][e] = (_Float16)(w - (float)hi);
            }
    __syncthreads();

    float Vacc = 0.f;
    const float* Pbase = P3 + wave * 16 * 1024 + lane * 4;  // 16 chunks per wave

    f32x4 p0 = *(const f32x4*)(Pbase + 0 * 256);
    f32x4 p1 = *(const f32x4*)(Pbase + 1 * 256);
    f32x4 p2 = *(const f32x4*)(Pbase + 2 * 256);
    f32x4 p3 = *(const f32x4*)(Pbase + 3 * 256);

    for (int k = 0; k < 16; k++) {
        int j0 = (wave * 16 + k) * 16;
        float d2 = d2s[j0 + nlo];

        // h1 tile in A-layout: row j0+nlo, k = quad*8+e per ktile; split to f16 hi/lo
        f16x8 aH[2], aL[2];
#pragma unroll
        for (int e2 = 0; e2 < 4; e2++) {
            {
                float h = tanh_fast(fmaf(d2, wzR[0][e2], aiR[0][e2] + p0[e2]));
                _Float16 hi = (_Float16)h;
                aH[0][e2] = hi; aL[0][e2] = (_Float16)(h - (float)hi);
            }
            {
                float h = tanh_fast(fmaf(d2, wzR[1][e2], aiR[1][e2] + p1[e2]));
                _Float16 hi = (_Float16)h;
                aH[0][4 + e2] = hi; aL[0][4 + e2] = (_Float16)(h - (float)hi);
            }
            {
                float h = tanh_fast(fmaf(d2, wzR[2][e2], aiR[2][e2] + p2[e2]));
                _Float16 hi = (_Float16)h;
                aH[1][e2] = hi; aL[1][e2] = (_Float16)(h - (float)hi);
            }
            {
                float h = tanh_fast(fmaf(d2, wzR[3][e2], aiR[3][e2] + p3[e2]));
                _Float16 hi = (_Float16)h;
                aH[1][4 + e2] = hi; aL[1][4 + e2] = (_Float16)(h - (float)hi);
            }
        }

        // prefetch next chunk's packed prejb
        if (k < 15) {
            const float* nb = Pbase + (k + 1) * 1024;
            p0 = *(const f32x4*)(nb + 0 * 256);
            p1 = *(const f32x4*)(nb + 1 * 256);
            p2 = *(const f32x4*)(nb + 2 * 256);
            p3 = *(const f32x4*)(nb + 3 * 256);
        }

        // S = h1 @ We2 (x3 split), then epilogue tanh + masked accumulate
#pragma unroll
        for (int nt = 0; nt < 4; nt++) {
            f32x4 acc = {0.f, 0.f, 0.f, 0.f};
#pragma unroll
            for (int kt = 0; kt < 2; kt++) {
                acc = __builtin_amdgcn_mfma_f32_16x16x32_f16(aH[kt], bH[nt][kt], acc, 0, 0, 0);
                acc = __builtin_amdgcn_mfma_f32_16x16x32_f16(aL[kt], bH[nt][kt], acc, 0, 0, 0);
                acc = __builtin_amdgcn_mfma_f32_16x16x32_f16(aH[kt], bL[nt][kt], acc, 0, 0, 0);
            }
            // C/D: col l = nt*16+nlo, row j-local = quad*4 + r
#pragma unroll
            for (int r = 0; r < 4; r++) {
                int jg = j0 + quad * 4 + r;
                float s = tanh_fast(acc[r] + be2R[nt]);
                Vacc += (jg != i) ? s : 0.f;
            }
        }
    }

    red[t] = Vacc;
    __syncthreads();
    if (t < 64) {
        float r = red[t] + red[t + 64] + red[t + 128] + red[t + 192];
#pragma unroll
        for (int o = 32; o > 0; o >>= 1) r += __shfl_down(r, o);
        if (t == 0) V[i] = r;
    }
}

// ---------------- Stage 3: post + finish fused ----------------
// 256 blocks x 256 threads, 4 atoms per block; out accumulated via atomicAdd.
__global__ __launch_bounds__(256) void k_postfin(const float* __restrict__ H,
                                                 const float* __restrict__ V,
                                                 const float* __restrict__ Wh1,
                                                 const float* __restrict__ bh1,
                                                 const float* __restrict__ Wh2,
                                                 const float* __restrict__ bh2,
                                                 const float* __restrict__ Wo,
                                                 const float* __restrict__ bo,
                                                 float* __restrict__ out) {
    int t = threadIdx.x;
    int sub = t >> 6, l = t & 63;
    int i = blockIdx.x * 4 + sub;
    __shared__ float hrow[4][L_DIM];
    __shared__ float hh[4][L_DIM];
    __shared__ float red[256];
    hrow[sub][l] = H[i * L_DIM + l];
    __syncthreads();
    float s = 0.f;
#pragma unroll
    for (int m = 0; m < L_DIM; m++) s = fmaf(hrow[sub][m], Wh1[m * L_DIM + l], s);
    s = fmaf(V[i], Wh1[L_DIM * L_DIM + l], s) + bh1[l];
    hh[sub][l] = tanh_fast(s);
    __syncthreads();
    float s2 = 0.f;
#pragma unroll
    for (int m = 0; m < L_DIM; m++) s2 = fmaf(hh[sub][m], Wh2[m * L_DIM + l], s2);
    float nh = tanh_fast(s2 + bh2[l]);
    red[t] = nh * Wo[l];
    __syncthreads();
    if (t < 64) {
        float r = red[t] + red[t + 64] + red[t + 128] + red[t + 192];
#pragma unroll
        for (int o = 32; o > 0; o >>= 1) r += __shfl_down(r, o);
        if (t == 0) {
            float add = r + (blockIdx.x == 0 ? bo[0] : 0.f);
            atomicAdd(out, add);
        }
    }
}

extern "C" void kernel_launch(void* const* d_in, const int* in_sizes, int n_in,
                              void* d_out, int out_size, void* d_ws, size_t ws_size,
                              hipStream_t stream) {
    const int*   cat = (const int*)  d_in[0];
    const float* Z   = (const float*)d_in[1];
    const float* LM  = (const float*)d_in[2];
    const float* We1 = (const float*)d_in[3];
    const float* be1 = (const float*)d_in[4];
    const float* We2 = (const float*)d_in[5];
    const float* be2 = (const float*)d_in[6];
    const float* Wh1 = (const float*)d_in[7];
    const float* bh1 = (const float*)d_in[8];
    const float* Wh2 = (const float*)d_in[9];
    const float* bh2 = (const float*)d_in[10];
    const float* Wo  = (const float*)d_in[11];
    const float* bo  = (const float*)d_in[12];
    float* out = (float*)d_out;

    float* ws   = (float*)d_ws;
    float* H    = ws;                       // 1024*64
    float* preI = H    + N_ATOMS * L_DIM;   // 1024*64
    float* P3   = preI + N_ATOMS * L_DIM;   // 1024*64 (packed prejb)
    float* V    = P3   + N_ATOMS * L_DIM;   // 1024

    hipMemsetAsync(out, 0, sizeof(float), stream);
    k_prep<<<N_ATOMS / 4, 256, 0, stream>>>(cat, LM, We1, be1, H, preI, P3);
    k_pairs<<<N_ATOMS, TPB, 0, stream>>>(Z, We1, We2, be2, preI, P3, V);
    k_postfin<<<N_ATOMS / 4, 256, 0, stream>>>(H, V, Wh1, bh1, Wh2, bh2, Wo, bo, out);
}